// Round 5
// baseline (14935.532 us; speedup 1.0000x reference)
//
#include <hip/hip_runtime.h>
#include <hip/hip_bf16.h>
#include <cstdint>
#include <cstddef>

typedef __bf16 bf16_t;
typedef __bf16 bf16x8 __attribute__((ext_vector_type(8)));
typedef __bf16 bf16x4 __attribute__((ext_vector_type(4)));
typedef float  floatx4 __attribute__((ext_vector_type(4)));

#define DEV static __device__ __forceinline__

DEV float sigm(float x) { return 1.f / (1.f + __expf(-x)); }

constexpr int E_ = 80000;   // edges
constexpr int N_ = 40000;   // nodes
// H = 128, IN = 384, NODE_FDIM = 256, MAX_NB = 6

// ---------------------------------------------------------------------------
// detect: classify input float width (bf16 vs f32) and index width (i32/i64).
// flags[0]=1 -> floats are f32; flags[1]=1 -> idx are i64.
// (Rounds 1/2 NaN with bf16 reads, rounds 3/4 finite with f32 reads => f32.)
// ---------------------------------------------------------------------------
__global__ void detect(const void* fmess, const void* bgraph, int* flags) {
  if (threadIdx.x == 0 && blockIdx.x == 0) {
    const uint16_t* w = (const uint16_t*)fmess;
    int good = 0;
    for (int j = 0; j < 128; ++j) {
      uint16_t x = w[j];
      int e = (x >> 7) & 0xFF;
      if (x == 0 || x == 0x8000 || (e >= 100 && e <= 140)) ++good;
    }
    flags[0] = (good < 110) ? 1 : 0;
    const uint32_t* q = (const uint32_t*)bgraph;
    int zeros = 0;
    for (int j = 0; j < 128; ++j)
      if (q[2 * j + 1] == 0u) ++zeros;
    flags[1] = (zeros >= 120) ? 1 : 0;
  }
}

DEV float rdf(const void* p, size_t i, bool f32) {
  return f32 ? ((const float*)p)[i] : (float)((const bf16_t*)p)[i];
}

// ---------------------------------------------------------------------------
// prep: dtype-aware transposed weight copies (BT[n][k] = W[k][n]) + bf16 bias
// copies.  WzT/WhT [128,512], WrT/WoT [128,384], UrT [128,128].
// ---------------------------------------------------------------------------
__launch_bounds__(256)
__global__ void prep(const void* Wz, const void* Wr, const void* Ur,
                     const void* Wh, const void* Wo,
                     const void* bz, const void* bur, const void* bh,
                     const void* bo, const int* flags,
                     bf16_t* WzT, bf16_t* WhT, bf16_t* WrT, bf16_t* UrT,
                     bf16_t* WoT, bf16_t* bzB, bf16_t* burB, bf16_t* bhB,
                     bf16_t* boB) {
  const bool f32 = flags[0] != 0;
  int i = blockIdx.x * blockDim.x + threadIdx.x;   // 65536 threads
  {  // 128 x 512
    int j = i >> 9, k = i & 511;
    WzT[i] = (bf16_t)rdf(Wz, (size_t)k * 128 + j, f32);
    WhT[i] = (bf16_t)rdf(Wh, (size_t)k * 128 + j, f32);
  }
  if (i < 128 * 384) {
    int j = i / 384, k = i % 384;
    WrT[i] = (bf16_t)rdf(Wr, (size_t)k * 128 + j, f32);
    WoT[i] = (bf16_t)rdf(Wo, (size_t)k * 128 + j, f32);
  }
  if (i < 128 * 128) {
    int j = i >> 7, k = i & 127;
    UrT[i] = (bf16_t)rdf(Ur, (size_t)k * 128 + j, f32);
  }
  if (i < 128) {
    bzB[i]  = (bf16_t)rdf(bz, i, f32);
    burB[i] = (bf16_t)rdf(bur, i, f32);
    bhB[i]  = (bf16_t)rdf(bh, i, f32);
    boB[i]  = (bf16_t)rdf(bo, i, f32);
  }
}

// ---------------------------------------------------------------------------
// idx_cvt: normalize agraph/bgraph to int32 ws copies.
// ---------------------------------------------------------------------------
__launch_bounds__(256)
__global__ void idx_cvt(const void* ag, const void* bg, int* aI, int* bI,
                        const int* flags) {
  const bool i64 = flags[1] != 0;
  int i = blockIdx.x * blockDim.x + threadIdx.x;   // 480000 threads
  if (i < N_ * 6)
    aI[i] = i64 ? (int)((const long long*)ag)[i] : ((const int*)ag)[i];
  if (i < E_ * 6)
    bI[i] = i64 ? (int)((const long long*)bg)[i] : ((const int*)bg)[i];
}

// ---------------------------------------------------------------------------
// NAIVE VALU GEMM (bisection: unchanged from round 4 except f32 C output).
// One thread per output element; f32 accumulate.
// ---------------------------------------------------------------------------
struct Pair {
  const void*   A;     // [Mrows, lda] bf16 ws (dyn=0) or external (dyn=1)
  int           lda;
  int           dyn;
  const bf16_t* BT;    // [128 cols, ldbt] transposed B (row n = k-run)
  int           ldbt;
  int           kOff;  // k offset into BT rows
  int           K;     // 0 => skip
};

DEV float dotp(const Pair p, bool af32, int row, int col) {
  if (p.K == 0) return 0.f;
  const bf16_t* bt = p.BT + (size_t)col * p.ldbt + p.kOff;
  float acc = 0.f;
  if (af32) {
    const float* a = (const float*)p.A + (size_t)row * p.lda;
    for (int k = 0; k < p.K; k += 8) {
      floatx4 a0 = *(const floatx4*)(a + k);
      floatx4 a1 = *(const floatx4*)(a + k + 4);
      bf16x8 b8 = *(const bf16x8*)(bt + k);
#pragma unroll
      for (int j = 0; j < 4; ++j) {
        acc += a0[j] * (float)b8[j];
        acc += a1[j] * (float)b8[4 + j];
      }
    }
  } else {
    const bf16_t* a = (const bf16_t*)p.A + (size_t)row * p.lda;
    for (int k = 0; k < p.K; k += 8) {
      bf16x8 a8 = *(const bf16x8*)(a + k);
      bf16x8 b8 = *(const bf16x8*)(bt + k);
#pragma unroll
      for (int j = 0; j < 8; ++j) acc += (float)a8[j] * (float)b8[j];
    }
  }
  return acc;
}

template <int MODE>
__launch_bounds__(256)
__global__ void ngemm(Pair p0, Pair p1, Pair p2, Pair p3, int Mrows,
                      const int* flags,
                      const bf16_t* bias0,  // MODE0 opt; MODE1 bz; MODE2 bo
                      const bf16_t* bias1,  // MODE1 bh
                      const bf16_t* Sb,     // MODE1: S bf16 [E,128] (null=>0)
                      bf16_t* Cb,           // bf16 out (null => skip)
                      float* Cf,            // f32 out  (null => skip)
                      int ldc) {
  const bool f32in = flags[0] != 0;
  int tid = threadIdx.x;
  int row = blockIdx.x * 2 + (tid >> 7);
  int col = tid & 127;
  if (row >= Mrows) return;
  float a1 = dotp(p0, p0.dyn && f32in, row, col)
           + dotp(p1, p1.dyn && f32in, row, col);
  float v;
  if (MODE == 0) {
    v = a1 + (bias0 ? (float)bias0[col] : 0.f);
  } else if (MODE == 1) {
    float a2 = dotp(p2, p2.dyn && f32in, row, col)
             + dotp(p3, p3.dyn && f32in, row, col);
    float z  = sigm(a1 + (float)bias0[col]);
    float ph = tanhf(a2 + (float)bias1[col]);
    float s  = Sb ? (float)Sb[(size_t)row * 128 + col] : 0.f;
    v = (1.f - z) * s + z * ph;
    if (row == 0) v = 0.f;
  } else {
    v = fmaxf(a1 + (float)bias0[col], 0.f);
    if (row == 0) v = 0.f;
  }
  if (Cb) Cb[(size_t)row * ldc + col] = (bf16_t)v;
  if (Cf) Cf[(size_t)row * ldc + col] = v;
}

// ---------------------------------------------------------------------------
// Gather+reduce per edge: S = sum h_nei, T = sum sigmoid(Mr + G_nei) * h_nei
// ---------------------------------------------------------------------------
__launch_bounds__(256)
__global__ void depth_gather(const bf16_t* h, const bf16_t* G, const bf16_t* Mr,
                             const int* bgraph, bf16_t* S, bf16_t* T) {
  int t = threadIdx.x;
  int e = blockIdx.x * 8 + (t >> 5);
  int c4 = (t & 31) * 4;
  bf16x4 mr = *(const bf16x4*)(Mr + (size_t)e * 128 + c4);
  float mrf[4];
#pragma unroll
  for (int j = 0; j < 4; ++j) mrf[j] = (float)mr[j];
  float sa[4] = {0.f, 0.f, 0.f, 0.f}, ta[4] = {0.f, 0.f, 0.f, 0.f};
  const int* bg = bgraph + (size_t)e * 6;
#pragma unroll
  for (int n = 0; n < 6; ++n) {
    int idx = bg[n];
    bf16x4 h4 = *(const bf16x4*)(h + (size_t)idx * 128 + c4);
    bf16x4 g4 = *(const bf16x4*)(G + (size_t)idx * 128 + c4);
#pragma unroll
    for (int j = 0; j < 4; ++j) {
      float hv = (float)h4[j];
      float r = sigm(mrf[j] + (float)g4[j]);
      sa[j] += hv;
      ta[j] += r * hv;
    }
  }
  bf16x4 sv, tv;
#pragma unroll
  for (int j = 0; j < 4; ++j) { sv[j] = (bf16_t)sa[j]; tv[j] = (bf16_t)ta[j]; }
  *(bf16x4*)(S + (size_t)e * 128 + c4) = sv;
  *(bf16x4*)(T + (size_t)e * 128 + c4) = tv;
}

// ---------------------------------------------------------------------------
// Node gather: NM[v] = sum_n h[agraph[v,n]]
// ---------------------------------------------------------------------------
__launch_bounds__(256)
__global__ void nm_gather(const bf16_t* h, const int* agraph, bf16_t* NM) {
  int t = threadIdx.x;
  int v = blockIdx.x * 8 + (t >> 5);
  int c4 = (t & 31) * 4;
  float sa[4] = {0.f, 0.f, 0.f, 0.f};
  const int* ag = agraph + (size_t)v * 6;
#pragma unroll
  for (int n = 0; n < 6; ++n) {
    int idx = ag[n];
    bf16x4 h4 = *(const bf16x4*)(h + (size_t)idx * 128 + c4);
#pragma unroll
    for (int j = 0; j < 4; ++j) sa[j] += (float)h4[j];
  }
  bf16x4 o;
#pragma unroll
  for (int j = 0; j < 4; ++j) o[j] = (bf16_t)sa[j];
  *(bf16x4*)(NM + (size_t)v * 128 + c4) = o;
}

// ---------------------------------------------------------------------------
extern "C" void kernel_launch(void* const* d_in, const int* in_sizes, int n_in,
                              void* d_out, int out_size, void* d_ws, size_t ws_size,
                              hipStream_t stream) {
  const void* fnode  = d_in[0];
  const void* fmess  = d_in[1];
  const void* agraph = d_in[2];
  const void* bgraph = d_in[3];
  const void* Wz  = d_in[4];
  const void* bz  = d_in[5];
  const void* Wr  = d_in[6];
  const void* Ur  = d_in[7];
  const void* bur = d_in[8];
  const void* Wh  = d_in[9];
  const void* bh  = d_in[10];
  const void* Wo  = d_in[11];
  const void* bo  = d_in[12];

  // workspace (~126 MB): 6 x [E,128] bf16 + weights + idx copies
  char* ws = (char*)d_ws;
  bf16_t* Mr  = (bf16_t*)ws; ws += (size_t)E_ * 128 * 2;  // fmess@Wr + bur
  bf16_t* G   = (bf16_t*)ws; ws += (size_t)E_ * 128 * 2;  // h@Ur; later NM
  bf16_t* S   = (bf16_t*)ws; ws += (size_t)E_ * 128 * 2;  // sum h_nei
  bf16_t* T   = (bf16_t*)ws; ws += (size_t)E_ * 128 * 2;  // sum r*h_nei
  bf16_t* hP0 = (bf16_t*)ws; ws += (size_t)E_ * 128 * 2;  // h ping
  bf16_t* hP1 = (bf16_t*)ws; ws += (size_t)E_ * 128 * 2;  // h pong
  bf16_t* WzT = (bf16_t*)ws; ws += 128 * 512 * 2;
  bf16_t* WhT = (bf16_t*)ws; ws += 128 * 512 * 2;
  bf16_t* WrT = (bf16_t*)ws; ws += 128 * 384 * 2;
  bf16_t* UrT = (bf16_t*)ws; ws += 128 * 128 * 2;
  bf16_t* WoT = (bf16_t*)ws; ws += 128 * 384 * 2;
  bf16_t* bzB  = (bf16_t*)ws; ws += 128 * 2;
  bf16_t* burB = (bf16_t*)ws; ws += 128 * 2;
  bf16_t* bhB  = (bf16_t*)ws; ws += 128 * 2;
  bf16_t* boB  = (bf16_t*)ws; ws += 128 * 2;
  int* aI    = (int*)ws; ws += (size_t)N_ * 6 * 4;
  int* bI    = (int*)ws; ws += (size_t)E_ * 6 * 4;
  int* flags = (int*)ws; ws += 16;

  // OUTPUT AS F32 (the reference's dtype): out0 [N,128] then h [E,128]
  float* out0F = (float*)d_out;
  float* hOutF = out0F + (size_t)N_ * 128;
  bf16_t* NM   = G;   // alias: G dead before nm_gather

  detect<<<1, 64, 0, stream>>>(fmess, bgraph, flags);
  prep<<<256, 256, 0, stream>>>(Wz, Wr, Ur, Wh, Wo, bz, bur, bh, bo, flags,
                                WzT, WhT, WrT, UrT, WoT, bzB, burB, bhB, boB);
  idx_cvt<<<1875, 256, 0, stream>>>(agraph, bgraph, aI, bI, flags);

  Pair z0{nullptr, 0, 0, nullptr, 0, 0, 0};

  // Mr = fmess @ Wr + bur   (loop-invariant)
  {
    Pair pr{fmess, 384, 1, WrT, 384, 0, 384};
    ngemm<0><<<E_ / 2, 256, 0, stream>>>(pr, z0, z0, z0, E_, flags, burB,
                                         nullptr, nullptr, Mr, nullptr, 128);
  }
  // depth 0: h = sig(fmess@Wz1+bz) * tanh(fmess@Wh1+bh)  (sum_h = 0)
  {
    Pair pz{fmess, 384, 1, WzT, 512, 0, 384};
    Pair ph{fmess, 384, 1, WhT, 512, 0, 384};
    ngemm<1><<<E_ / 2, 256, 0, stream>>>(pz, z0, ph, z0, E_, flags, bzB, bhB,
                                         nullptr, hP0, nullptr, 128);
  }

  const bf16_t* src = hP0;
  bf16_t* dst = hP1;
  for (int d = 0; d < 2; ++d) {
    // G = h @ Ur
    {
      Pair pg{src, 128, 0, UrT, 128, 0, 128};
      ngemm<0><<<E_ / 2, 256, 0, stream>>>(pg, z0, z0, z0, E_, flags, nullptr,
                                           nullptr, nullptr, G, nullptr, 128);
    }
    depth_gather<<<10000, 256, 0, stream>>>(src, G, Mr, bI, S, T);
    // h' = (1-z)*S + z*tanh(fmess@Wh1 + T@Wh2 + bh),
    //  z = sig(fmess@Wz1 + S@Wz2 + bz)
    {
      Pair pz1{fmess, 384, 1, WzT, 512, 0, 384};
      Pair pz2{S, 128, 0, WzT, 512, 384, 128};
      Pair ph1{fmess, 384, 1, WhT, 512, 0, 384};
      Pair ph2{T, 128, 0, WhT, 512, 384, 128};
      float* hF = (d == 1) ? hOutF : nullptr;  // final h also to d_out (f32)
      ngemm<1><<<E_ / 2, 256, 0, stream>>>(pz1, pz2, ph1, ph2, E_, flags, bzB,
                                           bhB, S, dst, hF, 128);
    }
    src = dst;
    dst = (d == 0) ? hP0 : hP1;
  }
  // final h (bf16) is in hP1 (d=1 wrote dst=hP1? no: d=0 wrote hP1, d=1 wrote hP0)
  const bf16_t* hFinal = hP0;   // d=1: src was hP1, dst was hP0

  nm_gather<<<5000, 256, 0, stream>>>(hFinal, aI, NM);

  // out = relu(fnode@Wo1 + NM@Wo2 + bo), row0 = 0   -> f32
  {
    Pair po1{fnode, 256, 1, WoT, 384, 0, 256};
    Pair po2{NM, 128, 0, WoT, 384, 256, 128};
    ngemm<2><<<N_ / 2, 256, 0, stream>>>(po1, po2, z0, z0, N_, flags, boB,
                                         nullptr, nullptr, nullptr, out0F, 128);
  }
}